// Round 6
// baseline (100.974 us; speedup 1.0000x reference)
//
#include <hip/hip_runtime.h>
#include <hip/hip_bf16.h>

#define BH 16
#define L 2048
#define S 2048
#define DD 64
#define BM 32                // L-rows per block (wave-pair splits the k-tile)
#define BK 64
#define LDSPAD 8
#define LDW (BK + LDSPAD)    // 72 elements -> 144B row stride, 16B aligned
#define NPITCH 68            // epilogue pitch: 68%32=4 -> at most 2-way (free)

typedef __attribute__((ext_vector_type(4))) float f32x4;
typedef __bf16 bf16x8 __attribute__((ext_vector_type(8)));

union FragU {
  bf16x8 f;
  __hip_bfloat162 h2[4];
};

__device__ inline __hip_bfloat162 exp2pack(float al2, float nsl2, float k0,
                                           float k1, float& d) {
  float e0 = __builtin_amdgcn_exp2f(fmaf(al2, k0, nsl2));
  float e1 = __builtin_amdgcn_exp2f(fmaf(al2, k1, nsl2));
  d += e0 + e1;
  return __float22bfloat162_rn(make_float2(e0, e1));
}

// ---------------------------------------------------------------------------
// prep: blocks [0,2048): K row sums (16 lanes per row).
//       blocks [2048,2560): V [bh][s][d] fp32 -> tiled VT2 bf16:
//       VT2[head][s/64][d][s%64], 8KB contiguous per 64x64 tile.
// ---------------------------------------------------------------------------
__global__ __launch_bounds__(256) void prep_kernel(
    const float* __restrict__ k, const float* __restrict__ v,
    float* __restrict__ ks, __hip_bfloat16* __restrict__ vt) {
  __shared__ __hip_bfloat16 tile[DD][LDW];
  int t = threadIdx.x;
  if (blockIdx.x < 2048) {
    int g = blockIdx.x * 256 + t;
    int row = g >> 4;
    int l16 = g & 15;
    float4 x = reinterpret_cast<const float4*>(k + (size_t)row * DD)[l16];
    float s = x.x + x.y + x.z + x.w;
    s += __shfl_xor(s, 1);
    s += __shfl_xor(s, 2);
    s += __shfl_xor(s, 4);
    s += __shfl_xor(s, 8);
    if (l16 == 0) ks[row] = s;
  } else {
    int bid = blockIdx.x - 2048;
    int bh = (bid & 7) * 2 + ((bid >> 3) & 1);
    int st = bid >> 4;        // s-tile 0..31
    int s0 = st * 64;
    int srow = t >> 4;
    int d4 = (t & 15) * 4;
#pragma unroll
    for (int kk = 0; kk < 4; ++kk) {
      int s = srow + kk * 16;
      float4 val = *reinterpret_cast<const float4*>(
          v + ((size_t)(bh * S + s0 + s)) * DD + d4);
      tile[d4 + 0][s] = __float2bfloat16(val.x);
      tile[d4 + 1][s] = __float2bfloat16(val.y);
      tile[d4 + 2][s] = __float2bfloat16(val.z);
      tile[d4 + 3][s] = __float2bfloat16(val.w);
    }
    __syncthreads();
    __hip_bfloat16* tb = vt + ((size_t)(bh * 32 + st)) * (DD * 64);
    int dd = t >> 3;
    int j = t & 7;
#pragma unroll
    for (int kk = 0; kk < 2; ++kk) {
      int d = dd + kk * 32;
      uint4 val = *reinterpret_cast<const uint4*>(&tile[d][j * 8]);
      *reinterpret_cast<uint4*>(tb + d * 64 + j * 8) = val;  // contiguous tile
    }
  }
}

// ---------------------------------------------------------------------------
// attn: block = 32 L-rows of one head; grid 1024 blocks -> 4 blocks/CU
// (round 5's 512-block grid capped occupancy at 2 blocks/CU). Wave w handles
// row-tile (w&1)*16 and k-half (w>>1)*32 of each 64-k LDS tile: 8 exps +
// 4 MFMAs + 4 b128 reads per wave per iter. Same measured-best staging:
// double-buffered LDS VT, register prefetch, ONE barrier per tile. Wave-pair
// (w, w+2) partials are additive; combined once via LDS in the epilogue.
// No launch_bounds min-waves (R3/R4 regressed with (256,4)).
// ---------------------------------------------------------------------------
__global__ __launch_bounds__(256) void attn_kernel(
    const float* __restrict__ q, const __hip_bfloat16* __restrict__ vt,
    const float* __restrict__ ks, float* __restrict__ out) {
  int bx = blockIdx.x;
  int bh = (bx & 7) * 2 + ((bx >> 3) & 1);  // XCD swizzle: 2 heads per XCD
  int l0 = (bx >> 4) * BM;

  __shared__ __hip_bfloat16 ldsVT[2][DD][LDW];
  __shared__ float numLDS[4][16][NPITCH];
  __shared__ float dLDS[4][16];
  __shared__ float a_row[BM];
  __shared__ float red[16];

  int t = threadIdx.x;
  int lane = t & 63;
  int w = t >> 6;
  int m = lane & 15;
  int qd = lane >> 4;        // quad 0..3
  int rt = (w & 1) * 16;     // this wave's row-tile base
  int kh = (w >> 1) * 32;    // this wave's k-half within the 64-k tile

  const __hip_bfloat16* vtb = vt + ((size_t)bh * 32) * (DD * 64);
  const float* ksb = ks + (size_t)bh * S;

  // --- prologue global prefetch: VT tile 0 (contiguous) + ksum chunk 0
  uint4 v0 = *reinterpret_cast<const uint4*>(vtb + t * 8);
  uint4 v1 = *reinterpret_cast<const uint4*>(vtb + 2048 + t * 8);
  float4 kv0 = *reinterpret_cast<const float4*>(ksb + kh + qd * 8);
  float4 kv1 = *reinterpret_cast<const float4*>(ksb + kh + qd * 8 + 4);

  // --- qsum for this block's 32 rows: 8 lanes per row
  {
    int r = t >> 3;
    int p = t & 7;
    const float* qp = q + ((size_t)(bh * L + l0 + r)) * DD + p * 8;
    float4 x0 = reinterpret_cast<const float4*>(qp)[0];
    float4 x1 = reinterpret_cast<const float4*>(qp)[1];
    float s = (x0.x + x0.y + x0.z + x0.w) + (x1.x + x1.y + x1.z + x1.w);
    s += __shfl_xor(s, 1);
    s += __shfl_xor(s, 2);
    s += __shfl_xor(s, 4);
    if (p == 0) a_row[r] = s;
  }

  // --- per-head kmax/kmin (identical in every block of this head)
  {
    const float* kp = ksb + t * 8;
    float4 y0 = reinterpret_cast<const float4*>(kp)[0];
    float4 y1 = reinterpret_cast<const float4*>(kp)[1];
    float mx = fmaxf(fmaxf(fmaxf(y0.x, y0.y), fmaxf(y0.z, y0.w)),
                     fmaxf(fmaxf(y1.x, y1.y), fmaxf(y1.z, y1.w)));
    float mn = fminf(fminf(fminf(y0.x, y0.y), fminf(y0.z, y0.w)),
                     fminf(fminf(y1.x, y1.y), fminf(y1.z, y1.w)));
#pragma unroll
    for (int off = 1; off < 64; off <<= 1) {
      mx = fmaxf(mx, __shfl_xor(mx, off));
      mn = fminf(mn, __shfl_xor(mn, off));
    }
    if (lane == 0) {
      red[w] = mx;
      red[8 + w] = mn;
    }
  }
  __syncthreads();

  float kmax = fmaxf(fmaxf(red[0], red[1]), fmaxf(red[2], red[3]));
  float kmin = fminf(fminf(red[8], red[9]), fminf(red[10], red[11]));
  float ar = a_row[rt + m];  // this lane's E-row coefficient
  float sel = (ar > 0.f) ? kmax : kmin;
  const float LOG2E = 1.44269504088896f;
  float al2 = ar * LOG2E;
  float nsl2 = -al2 * sel;

  float dsum = 0.f;
  f32x4 acc[4];
#pragma unroll
  for (int c = 0; c < 4; ++c) acc[c] = (f32x4){0.f, 0.f, 0.f, 0.f};

  for (int it = 0; it < 32; ++it) {
    int bufi = it & 1;
    // store prefetched VT tile: element e = t*8 -> d=e>>6, s=e&63
    *reinterpret_cast<uint4*>(&ldsVT[bufi][t >> 3][(t & 7) * 8]) = v0;
    *reinterpret_cast<uint4*>(&ldsVT[bufi][32 + (t >> 3)][(t & 7) * 8]) = v1;
    __syncthreads();  // the ONLY barrier per tile

    int itn = (it < 31) ? it + 1 : 31;  // clamped prefetch
    const __hip_bfloat16* tn = vtb + (size_t)itn * (DD * 64);
    v0 = *reinterpret_cast<const uint4*>(tn + t * 8);
    v1 = *reinterpret_cast<const uint4*>(tn + 2048 + t * 8);
    int s0n = itn * BK;

    // A-frag: E[rt+m][kh + qd*8 + j], 8 exps per lane
    FragU f0;
    f0.h2[0] = exp2pack(al2, nsl2, kv0.x, kv0.y, dsum);
    f0.h2[1] = exp2pack(al2, nsl2, kv0.z, kv0.w, dsum);
    f0.h2[2] = exp2pack(al2, nsl2, kv1.x, kv1.y, dsum);
    f0.h2[3] = exp2pack(al2, nsl2, kv1.z, kv1.w, dsum);

    // prefetch next ksum chunk
    kv0 = *reinterpret_cast<const float4*>(ksb + s0n + kh + qd * 8);
    kv1 = *reinterpret_cast<const float4*>(ksb + s0n + kh + qd * 8 + 4);

    // 4 MFMAs: rows [rt,rt+16) x 64 cols, this wave's k-half
#pragma unroll
    for (int c = 0; c < 4; ++c) {
      uint4 bu =
          *reinterpret_cast<const uint4*>(&ldsVT[bufi][c * 16 + m][kh + qd * 8]);
      acc[c] = __builtin_amdgcn_mfma_f32_16x16x32_bf16(
          f0.f, __builtin_bit_cast(bf16x8, bu), acc[c], 0, 0, 0);
    }
  }

  // per-wave row denominators (lanes m, m+16, m+32, m+48 share row rt+m)
  float dt = dsum;
  dt += __shfl_xor(dt, 16);
  dt += __shfl_xor(dt, 32);
  if (qd == 0) dLDS[w][m] = dt;
  // per-wave partial numerators (C layout: col=lane&15, row=quad*4+reg)
#pragma unroll
  for (int c = 0; c < 4; ++c)
#pragma unroll
    for (int i = 0; i < 4; ++i)
      numLDS[w][qd * 4 + i][c * 16 + m] = acc[c][i];
  __syncthreads();

  // combine wave pairs (w, w+2) + normalize + coalesced store
  {
    int r = t >> 3;            // 0..31
    int cg = (t & 7) * 8;
    int wlo = (r >> 4) & 1;    // rows 0-15 <- waves 0,2; rows 16-31 <- 1,3
    int rr = r & 15;
    float4 n0 = *reinterpret_cast<const float4*>(&numLDS[wlo][rr][cg]);
    float4 n1 = *reinterpret_cast<const float4*>(&numLDS[wlo][rr][cg + 4]);
    float4 p0 = *reinterpret_cast<const float4*>(&numLDS[wlo + 2][rr][cg]);
    float4 p1 = *reinterpret_cast<const float4*>(&numLDS[wlo + 2][rr][cg + 4]);
    n0.x += p0.x; n0.y += p0.y; n0.z += p0.z; n0.w += p0.w;
    n1.x += p1.x; n1.y += p1.y; n1.z += p1.z; n1.w += p1.w;
    float inv = 1.0f / (dLDS[wlo][rr] + dLDS[wlo + 2][rr]);
    n0.x *= inv; n0.y *= inv; n0.z *= inv; n0.w *= inv;
    n1.x *= inv; n1.y *= inv; n1.z *= inv; n1.w *= inv;
    float* ob = out + ((size_t)(bh * L + l0 + r)) * DD + cg;
    reinterpret_cast<float4*>(ob)[0] = n0;
    reinterpret_cast<float4*>(ob)[1] = n1;
  }
}

extern "C" void kernel_launch(void* const* d_in, const int* in_sizes, int n_in,
                              void* d_out, int out_size, void* d_ws,
                              size_t ws_size, hipStream_t stream) {
  const float* q = (const float*)d_in[0];
  const float* k = (const float*)d_in[1];
  const float* v = (const float*)d_in[2];
  float* out = (float*)d_out;
  float* ws = (float*)d_ws;

  float* ks = ws;  // BH*S = 32768 floats
  __hip_bfloat16* vt = (__hip_bfloat16*)(ws + BH * S);  // tiled VT2, 4MB

  prep_kernel<<<2048 + 512, 256, 0, stream>>>(k, v, ks, vt);
  attn_kernel<<<(L / BM) * BH, 256, 0, stream>>>(q, vt, ks, out);
}

// Round 7
// 98.088 us; speedup vs baseline: 1.0294x; 1.0294x over previous
//
#include <hip/hip_runtime.h>
#include <hip/hip_bf16.h>

#define BH 16
#define L 2048
#define S 2048
#define DD 64
#define BM 64
#define BK 128               // two 64x64 sub-tiles staged per barrier
#define LDSPAD 8
#define LDW2 (BK + LDSPAD)   // 136 elem pitch: 68 dwords, 68%32=4 -> 2-way max
#define LDWP (DD + LDSPAD)   // prep transpose tile pitch
#define NPITCH 68            // epilogue pitch (floats): 2-way max (free)

typedef __attribute__((ext_vector_type(4))) float f32x4;
typedef __bf16 bf16x8 __attribute__((ext_vector_type(8)));

union FragU {
  bf16x8 f;
  __hip_bfloat162 h2[4];
};

__device__ inline __hip_bfloat162 exp2pack(float al2, float nsl2, float k0,
                                           float k1, float& d) {
  float e0 = __builtin_amdgcn_exp2f(fmaf(al2, k0, nsl2));
  float e1 = __builtin_amdgcn_exp2f(fmaf(al2, k1, nsl2));
  d += e0 + e1;
  return __float22bfloat162_rn(make_float2(e0, e1));
}

// ---------------------------------------------------------------------------
// prep: blocks [0,2048): K row sums (16 lanes per row).
//       blocks [2048,2560): V [bh][s][d] fp32 -> tiled VT2 bf16:
//       VT2[head][s/64][d][s%64], 8KB contiguous per 64x64 tile.
// ---------------------------------------------------------------------------
__global__ __launch_bounds__(256) void prep_kernel(
    const float* __restrict__ k, const float* __restrict__ v,
    float* __restrict__ ks, __hip_bfloat16* __restrict__ vt) {
  __shared__ __hip_bfloat16 tile[DD][LDWP];
  int t = threadIdx.x;
  if (blockIdx.x < 2048) {
    int g = blockIdx.x * 256 + t;
    int row = g >> 4;
    int l16 = g & 15;
    float4 x = reinterpret_cast<const float4*>(k + (size_t)row * DD)[l16];
    float s = x.x + x.y + x.z + x.w;
    s += __shfl_xor(s, 1);
    s += __shfl_xor(s, 2);
    s += __shfl_xor(s, 4);
    s += __shfl_xor(s, 8);
    if (l16 == 0) ks[row] = s;
  } else {
    int bid = blockIdx.x - 2048;
    int bh = (bid & 7) * 2 + ((bid >> 3) & 1);
    int st = bid >> 4;        // s-tile 0..31
    int s0 = st * 64;
    int srow = t >> 4;
    int d4 = (t & 15) * 4;
#pragma unroll
    for (int kk = 0; kk < 4; ++kk) {
      int s = srow + kk * 16;
      float4 val = *reinterpret_cast<const float4*>(
          v + ((size_t)(bh * S + s0 + s)) * DD + d4);
      tile[d4 + 0][s] = __float2bfloat16(val.x);
      tile[d4 + 1][s] = __float2bfloat16(val.y);
      tile[d4 + 2][s] = __float2bfloat16(val.z);
      tile[d4 + 3][s] = __float2bfloat16(val.w);
    }
    __syncthreads();
    __hip_bfloat16* tb = vt + ((size_t)(bh * 32 + st)) * (DD * 64);
    int dd = t >> 3;
    int j = t & 7;
#pragma unroll
    for (int kk = 0; kk < 2; ++kk) {
      int d = dd + kk * 32;
      uint4 val = *reinterpret_cast<const uint4*>(&tile[d][j * 8]);
      *reinterpret_cast<uint4*>(tb + d * 64 + j * 8) = val;  // contiguous tile
    }
  }
}

// ---------------------------------------------------------------------------
// attn: block = 64 L-rows of one head; 2x2 (row,k) wave split:
// wave w = (wr=w&1, wk=w>>1) computes rows wr*32+[0,32) x k-half wk*32.
// Each wave reads only 1/4 of the staged B per sub-tile (halves block LDS
// read traffic vs the R5 all-rows split). BK=128 stages TWO 64x64 VT tiles
// per barrier -> 16 barriers total (vs 32). E in A-frag registers, register
// prefetch of globals, ONE barrier per staged pair. (wr,wk) partial
// numerators/denominators combined once via LDS in the epilogue.
// ---------------------------------------------------------------------------
__global__ __launch_bounds__(256) void attn_kernel(
    const float* __restrict__ q, const __hip_bfloat16* __restrict__ vt,
    const float* __restrict__ ks, float* __restrict__ out) {
  int bx = blockIdx.x;
  int bh = (bx & 7) * 2 + ((bx >> 3) & 1);  // XCD swizzle: 2 heads per XCD
  int l0 = (bx >> 4) * BM;

  __shared__ __hip_bfloat16 ldsVT[2][DD][LDW2];
  __shared__ float numLDS[4][32][NPITCH];
  __shared__ float dLDS[4][32];
  __shared__ float a_row[BM];
  __shared__ float red[16];

  int t = threadIdx.x;
  int lane = t & 63;
  int w = t >> 6;
  int m = lane & 15;
  int qd = lane >> 4;        // quad 0..3
  int wr = w & 1;            // row-half: rows wr*32 + [0,32)
  int wk = w >> 1;           // k-half within each 64-k sub-tile
  int kh = wk * 32;

  const __hip_bfloat16* vtb = vt + ((size_t)bh * 32) * (DD * 64);
  const float* ksb = ks + (size_t)bh * S;

  // --- prologue global prefetch: VT tiles 0,1 (16KB contiguous) + ksum
  uint4 v0 = *reinterpret_cast<const uint4*>(vtb + t * 8);
  uint4 v1 = *reinterpret_cast<const uint4*>(vtb + 2048 + t * 8);
  uint4 v2 = *reinterpret_cast<const uint4*>(vtb + 4096 + t * 8);
  uint4 v3 = *reinterpret_cast<const uint4*>(vtb + 6144 + t * 8);
  float4 kv0 = *reinterpret_cast<const float4*>(ksb + kh + qd * 8);
  float4 kv1 = *reinterpret_cast<const float4*>(ksb + kh + qd * 8 + 4);
  float4 kv2 = *reinterpret_cast<const float4*>(ksb + 64 + kh + qd * 8);
  float4 kv3 = *reinterpret_cast<const float4*>(ksb + 64 + kh + qd * 8 + 4);

  // --- qsum for this block's 64 rows: 4 lanes per row
  {
    int r = t >> 2;
    int p = t & 3;
    const float* qp = q + ((size_t)(bh * L + l0 + r)) * DD + p * 16;
    float4 x0 = reinterpret_cast<const float4*>(qp)[0];
    float4 x1 = reinterpret_cast<const float4*>(qp)[1];
    float4 x2 = reinterpret_cast<const float4*>(qp)[2];
    float4 x3 = reinterpret_cast<const float4*>(qp)[3];
    float s = (x0.x + x0.y + x0.z + x0.w) + (x1.x + x1.y + x1.z + x1.w) +
              (x2.x + x2.y + x2.z + x2.w) + (x3.x + x3.y + x3.z + x3.w);
    s += __shfl_xor(s, 1);
    s += __shfl_xor(s, 2);
    if (p == 0) a_row[r] = s;
  }

  // --- per-head kmax/kmin (identical in every block of this head)
  {
    const float* kp = ksb + t * 8;
    float4 y0 = reinterpret_cast<const float4*>(kp)[0];
    float4 y1 = reinterpret_cast<const float4*>(kp)[1];
    float mx = fmaxf(fmaxf(fmaxf(y0.x, y0.y), fmaxf(y0.z, y0.w)),
                     fmaxf(fmaxf(y1.x, y1.y), fmaxf(y1.z, y1.w)));
    float mn = fminf(fminf(fminf(y0.x, y0.y), fminf(y0.z, y0.w)),
                     fminf(fminf(y1.x, y1.y), fminf(y1.z, y1.w)));
#pragma unroll
    for (int off = 1; off < 64; off <<= 1) {
      mx = fmaxf(mx, __shfl_xor(mx, off));
      mn = fminf(mn, __shfl_xor(mn, off));
    }
    if (lane == 0) {
      red[w] = mx;
      red[8 + w] = mn;
    }
  }
  __syncthreads();

  float kmax = fmaxf(fmaxf(red[0], red[1]), fmaxf(red[2], red[3]));
  float kmin = fminf(fminf(red[8], red[9]), fminf(red[10], red[11]));
  const float LOG2E = 1.44269504088896f;
  float ar0 = a_row[wr * 32 + m];       // A-frag rows wr*32 + [0,16)
  float ar1 = a_row[wr * 32 + 16 + m];  // A-frag rows wr*32 + [16,32)
  float al20 = ar0 * LOG2E, al21 = ar1 * LOG2E;
  float nsl20 = -al20 * ((ar0 > 0.f) ? kmax : kmin);
  float nsl21 = -al21 * ((ar1 > 0.f) ? kmax : kmin);

  float ds0 = 0.f, ds1 = 0.f;
  f32x4 acc[2][4];
#pragma unroll
  for (int a = 0; a < 2; ++a)
#pragma unroll
    for (int c = 0; c < 4; ++c) acc[a][c] = (f32x4){0.f, 0.f, 0.f, 0.f};

  for (int it = 0; it < S / BK; ++it) {
    int bufi = it & 1;
    // store prefetched pair of VT tiles: element e = t*8 -> d=e>>6, s=e&63
    {
      int d = t >> 3;
      int s8 = (t & 7) * 8;
      *reinterpret_cast<uint4*>(&ldsVT[bufi][d][s8]) = v0;
      *reinterpret_cast<uint4*>(&ldsVT[bufi][32 + d][s8]) = v1;
      *reinterpret_cast<uint4*>(&ldsVT[bufi][d][64 + s8]) = v2;
      *reinterpret_cast<uint4*>(&ldsVT[bufi][32 + d][64 + s8]) = v3;
    }
    __syncthreads();  // the ONLY barrier per 128-k pair

    int itn = (it < S / BK - 1) ? it + 1 : it;  // clamped prefetch
    const __hip_bfloat16* tn = vtb + (size_t)itn * (2 * DD * 64);
    v0 = *reinterpret_cast<const uint4*>(tn + t * 8);
    v1 = *reinterpret_cast<const uint4*>(tn + 2048 + t * 8);
    v2 = *reinterpret_cast<const uint4*>(tn + 4096 + t * 8);
    v3 = *reinterpret_cast<const uint4*>(tn + 6144 + t * 8);
    int s0n = itn * BK;

    // ---- sub-tile 0: A-frags (8 exps each row-half), 8 MFMAs
    FragU f0, f1;
    f0.h2[0] = exp2pack(al20, nsl20, kv0.x, kv0.y, ds0);
    f0.h2[1] = exp2pack(al20, nsl20, kv0.z, kv0.w, ds0);
    f0.h2[2] = exp2pack(al20, nsl20, kv1.x, kv1.y, ds0);
    f0.h2[3] = exp2pack(al20, nsl20, kv1.z, kv1.w, ds0);
    f1.h2[0] = exp2pack(al21, nsl21, kv0.x, kv0.y, ds1);
    f1.h2[1] = exp2pack(al21, nsl21, kv0.z, kv0.w, ds1);
    f1.h2[2] = exp2pack(al21, nsl21, kv1.x, kv1.y, ds1);
    f1.h2[3] = exp2pack(al21, nsl21, kv1.z, kv1.w, ds1);
#pragma unroll
    for (int c = 0; c < 4; ++c) {
      uint4 bu =
          *reinterpret_cast<const uint4*>(&ldsVT[bufi][c * 16 + m][kh + qd * 8]);
      bf16x8 bf = __builtin_bit_cast(bf16x8, bu);
      acc[0][c] = __builtin_amdgcn_mfma_f32_16x16x32_bf16(f0.f, bf, acc[0][c],
                                                          0, 0, 0);
      acc[1][c] = __builtin_amdgcn_mfma_f32_16x16x32_bf16(f1.f, bf, acc[1][c],
                                                          0, 0, 0);
    }

    // ---- sub-tile 1
    f0.h2[0] = exp2pack(al20, nsl20, kv2.x, kv2.y, ds0);
    f0.h2[1] = exp2pack(al20, nsl20, kv2.z, kv2.w, ds0);
    f0.h2[2] = exp2pack(al20, nsl20, kv3.x, kv3.y, ds0);
    f0.h2[3] = exp2pack(al20, nsl20, kv3.z, kv3.w, ds0);
    f1.h2[0] = exp2pack(al21, nsl21, kv2.x, kv2.y, ds1);
    f1.h2[1] = exp2pack(al21, nsl21, kv2.z, kv2.w, ds1);
    f1.h2[2] = exp2pack(al21, nsl21, kv3.x, kv3.y, ds1);
    f1.h2[3] = exp2pack(al21, nsl21, kv3.z, kv3.w, ds1);

    // prefetch next ksum chunks
    kv0 = *reinterpret_cast<const float4*>(ksb + s0n + kh + qd * 8);
    kv1 = *reinterpret_cast<const float4*>(ksb + s0n + kh + qd * 8 + 4);
    kv2 = *reinterpret_cast<const float4*>(ksb + s0n + 64 + kh + qd * 8);
    kv3 = *reinterpret_cast<const float4*>(ksb + s0n + 64 + kh + qd * 8 + 4);

#pragma unroll
    for (int c = 0; c < 4; ++c) {
      uint4 bu = *reinterpret_cast<const uint4*>(
          &ldsVT[bufi][c * 16 + m][64 + kh + qd * 8]);
      bf16x8 bf = __builtin_bit_cast(bf16x8, bu);
      acc[0][c] = __builtin_amdgcn_mfma_f32_16x16x32_bf16(f0.f, bf, acc[0][c],
                                                          0, 0, 0);
      acc[1][c] = __builtin_amdgcn_mfma_f32_16x16x32_bf16(f1.f, bf, acc[1][c],
                                                          0, 0, 0);
    }
  }

  // per-wave row denominators for this k-half (lanes m..m+48 share a row)
  ds0 += __shfl_xor(ds0, 16);
  ds0 += __shfl_xor(ds0, 32);
  ds1 += __shfl_xor(ds1, 16);
  ds1 += __shfl_xor(ds1, 32);
  if (qd == 0) {
    dLDS[w][m] = ds0;
    dLDS[w][16 + m] = ds1;
  }
  // per-wave partial numerators (C layout: col=lane&15, row=quad*4+reg)
#pragma unroll
  for (int a = 0; a < 2; ++a)
#pragma unroll
    for (int c = 0; c < 4; ++c)
#pragma unroll
      for (int i = 0; i < 4; ++i)
        numLDS[w][a * 16 + qd * 4 + i][c * 16 + m] = acc[a][c][i];
  __syncthreads();

  // combine k-half wave pairs (w, w+2) + normalize + coalesced store
  {
    int r = t >> 2;            // 0..63
    int cg = (t & 3) * 16;     // 16 cols per thread
    int lr = r & 31;
    int wlo = r >> 5;          // rows 0-31 <- waves 0,2 ; rows 32-63 <- 1,3
    float inv = 1.0f / (dLDS[wlo][lr] + dLDS[wlo + 2][lr]);
    float* ob = out + ((size_t)(bh * L + l0 + r)) * DD + cg;
#pragma unroll
    for (int u = 0; u < 4; ++u) {
      float4 n = *reinterpret_cast<const float4*>(&numLDS[wlo][lr][cg + u * 4]);
      float4 p =
          *reinterpret_cast<const float4*>(&numLDS[wlo + 2][lr][cg + u * 4]);
      n.x = (n.x + p.x) * inv;
      n.y = (n.y + p.y) * inv;
      n.z = (n.z + p.z) * inv;
      n.w = (n.w + p.w) * inv;
      reinterpret_cast<float4*>(ob)[u] = n;
    }
  }
}

extern "C" void kernel_launch(void* const* d_in, const int* in_sizes, int n_in,
                              void* d_out, int out_size, void* d_ws,
                              size_t ws_size, hipStream_t stream) {
  const float* q = (const float*)d_in[0];
  const float* k = (const float*)d_in[1];
  const float* v = (const float*)d_in[2];
  float* out = (float*)d_out;
  float* ws = (float*)d_ws;

  float* ks = ws;  // BH*S = 32768 floats
  __hip_bfloat16* vt = (__hip_bfloat16*)(ws + BH * S);  // tiled VT2, 4MB

  prep_kernel<<<2048 + 512, 256, 0, stream>>>(k, v, ks, vt);
  attn_kernel<<<(L / BM) * BH, 256, 0, stream>>>(q, vt, ks, out);
}